// Round 14
// baseline (2211.940 us; speedup 1.0000x reference)
//
#include <hip/hip_runtime.h>

constexpr int BB = 64, TT = 512, DD = 512, HH = 512;
constexpr int GG = 4 * HH;          // 2048 gate cols
constexpr int KK = DD + HH;         // 1024 fused K
constexpr int NBLK = 128, NTHR = 512;
// LDS: smx[8][1024B] swz | smh[8][1024B] swz | mask[8][16]
constexpr int LDS_BYTES = 8192 + 8192 + 512;

using short8 = __attribute__((ext_vector_type(8))) short;
using f32x4  = __attribute__((ext_vector_type(4))) float;

__device__ __host__ __forceinline__ unsigned short f2bf(float f) {
    union { float f; unsigned u; } v; v.f = f;
    unsigned u = v.u + 0x7fffu + ((v.u >> 16) & 1u);   // RNE
    return (unsigned short)(u >> 16);
}
__device__ __forceinline__ float fsig(float x) {
    return 1.f / (1.f + __expf(-x));
}
__device__ __forceinline__ float ftanh_(float x) {
    float e = __expf(2.f * fabsf(x));
    float r = 1.f - 2.f / (e + 1.f);
    return copysignf(r, x);
}

// ws: WB[2048][1024] bf16 (4MB) | hbuf[8 grp][2][8][256] u32 (128KB)
//     | flags[8 grp][16][16pad] (8KB) | mpack[64][16] (4KB)

__global__ void prep_kernel(const float* __restrict__ Wx,
                            const float* __restrict__ Wr,
                            const float* __restrict__ init_h,
                            const int*   __restrict__ mask,
                            unsigned short* __restrict__ WB,
                            unsigned* __restrict__ hbuf0,
                            unsigned* __restrict__ flags,
                            unsigned* __restrict__ mpack) {
    int idx = blockIdx.x * blockDim.x + threadIdx.x;
    if (idx < GG * KK) {                 // WB[g][k] = W[k][g], bf16
        int g = idx >> 10, k = idx & 1023;
        float v = (k < DD) ? Wx[(size_t)k * GG + g]
                           : Wr[(size_t)(k - DD) * GG + g];
        WB[idx] = f2bf(v);
    }
    if (idx < BB * HH / 2) {             // h0 pairs into [grp][buf0][row][256]
        int b = idx >> 8, p = idx & 255;
        unsigned lo = f2bf(init_h[b * HH + 2 * p]);
        unsigned hi = f2bf(init_h[b * HH + 2 * p + 1]);
        hbuf0[(b >> 3) * 4096 + (b & 7) * 256 + p] = lo | (hi << 16);
    }
    if (idx < 2048) flags[idx] = 0u;
    if (idx < 64 * 16) {
        int b = idx >> 4, w = idx & 15;
        unsigned word = 0u;
        for (int tb = 0; tb < 32; ++tb)
            word |= (mask[b * TT + w * 32 + tb] != 0 ? 1u : 0u) << tb;
        mpack[idx] = word;
    }
}

__global__ void __launch_bounds__(NTHR, 1)
lstm_kernel(const float* __restrict__ x,
            const unsigned short* __restrict__ WB,
            const float* __restrict__ bias,
            unsigned*    hbuf,                    // sc1-only traffic
            unsigned*    flags,                   // sc1-only, line-padded
            const unsigned* __restrict__ mpack,
            const float* __restrict__ init_h,
            const float* __restrict__ init_c,
            float* __restrict__ out)
{
    extern __shared__ char smem[];
    char*     smx   = smem;                       // x A-tile [8][1024B] swz
    char*     smh   = smem + 8192;                // h A-tile [8][1024B] swz
    unsigned* m_lds = (unsigned*)(smem + 16384);  // [8][16]

    const int tid = threadIdx.x;
    const int bid = blockIdx.x;
    const int w   = tid >> 6;          // wave 0..7: owns j-cols w*4..w*4+3
    const int l   = tid & 63;

    const int grp    = bid & 7;        // batch octet: rows grp*8..+7
    const int qb     = bid >> 3;       // j-slice 0..15
    const int j_base = qb * 32;
    const int obase  = grp * 8;

    // ---- persistent B-fragments: 32 ktiles, custom col set ----
    // col n = (jlw<<2)|gate : gate = n&3, jlw = n>>2  (j = j_base + w*4 + jlw)
    short8 bf[32];
    {
        int n = l & 15;
        int g = (n & 3) * 512 + j_base + w * 4 + (n >> 2);
        const unsigned short* wrow = WB + (size_t)g * KK + (l >> 4) * 8;
        #pragma unroll
        for (int kt = 0; kt < 32; ++kt)
            bf[kt] = *(const short8*)(wrow + kt * 32);
    }

    // ---- per-lane update state: 4 rows x 1 j-col (4-lane-group duplicated) ----
    const int gt   = l & 3;            // gate this lane's col carries
    const int jlw  = (l >> 2) & 3;     // j within wave's 4
    const int jloc = w * 4 + jlw;      // 0..31 local j
    const int jg   = j_base + jloc;    // global j
    const int rq   = (l >> 4) & 1;     // row quad 0: rows 0-3, 1: rows 4-7
    float c_reg[4] = {0,0,0,0}, h_reg[4] = {0,0,0,0}, po_reg[4] = {0,0,0,0};
    float bz = 0.f;
    if (l < 32) {
        bz = bias[gt * 512 + jg];
        #pragma unroll
        for (int r = 0; r < 4; ++r) {
            int row_g = obase + rq * 4 + r;
            c_reg[r] = init_c[row_g * HH + jg];
            h_reg[r] = init_h[row_g * HH + jg];
        }
    }
    for (int i = tid; i < 128; i += NTHR)
        m_lds[i] = mpack[(obase + (i >> 4)) * 16 + (i & 15)];

    unsigned* hgrp = hbuf + grp * 4096;            // [2][8][256]
    const size_t OUT_HF = (size_t)BB * TT * HH;
    const size_t OUT_CF = OUT_HF + (size_t)BB * HH;
    const int arow = l & 7;            // A row (lanes 8-15 duplicate rows 0-7)
    const int rsw  = arow << 4;

    // ---- prologue: stage x[0] (512 threads, 1 short8 each) ----
    {
        int row = tid >> 6, c = tid & 63;
        const float4* xp = (const float4*)(
            x + ((size_t)(obase + row) * TT + 0) * DD + 8 * c);
        float4 f0 = xp[0], f1 = xp[1];
        short8 v;
        v[0] = (short)f2bf(f0.x); v[1] = (short)f2bf(f0.y);
        v[2] = (short)f2bf(f0.z); v[3] = (short)f2bf(f0.w);
        v[4] = (short)f2bf(f1.x); v[5] = (short)f2bf(f1.y);
        v[6] = (short)f2bf(f1.z); v[7] = (short)f2bf(f1.w);
        *(short8*)(smx + row * 1024 + ((16 * c) ^ ((row & 7) << 4))) = v;
    }
    __syncthreads();

    for (int t = 0; t < TT; ++t) {
        // ---- (1) poll own group's 16 line-padded flags (all waves) ----
        {
            const unsigned tgt = (unsigned)t;
            const unsigned* fb = flags + grp * 256 + (l & 15) * 16;
            for (;;) {
                unsigned v = __hip_atomic_load(fb, __ATOMIC_RELAXED,
                                               __HIP_MEMORY_SCOPE_AGENT);
                if (__all(v >= tgt)) break;
                __builtin_amdgcn_s_sleep(1);
            }
        }

        // ---- (2) issue h row load: wave w -> row w (1KB, coalesced sc1) ----
        const unsigned* curb = hgrp + (size_t)(t & 1) * 2048;
        unsigned*       nxtb = hgrp + (size_t)((t + 1) & 1) * 2048;
        uint4 hv;
        {
            const unsigned* hp = curb + w * 256 + l * 4;
            asm volatile("global_load_dwordx4 %0, %1, off sc1"
                         : "=v"(hv) : "v"(hp) : "memory");
        }

        // ---- (3) 16 x-MFMAs (all K in-wave) hide the h-load latency ----
        f32x4 acc = {0.f, 0.f, 0.f, 0.f};
        #pragma unroll
        for (int kt = 0; kt < 16; ++kt) {
            short8 a = *(const short8*)(
                smx + arow * 1024 + ((kt * 64 + (l >> 4) * 16) ^ rsw));
            acc = __builtin_amdgcn_mfma_f32_16x16x32_bf16(a, bf[kt], acc, 0, 0, 0);
        }

        // ---- (4) wait h, stage into LDS ----
        asm volatile("s_waitcnt vmcnt(0)" ::: "memory");
        __builtin_amdgcn_sched_barrier(0);
        {
            union { uint4 u; short8 s; } cv; cv.u = hv;
            *(short8*)(smh + w * 1024 + ((l * 16) ^ ((w & 7) << 4))) = cv.s;
        }
        __syncthreads();   // bar A: smh ready (also: all smx reads for t done)

        // ---- (5) 16 h-MFMAs: z complete in-wave ----
        #pragma unroll
        for (int kt = 0; kt < 16; ++kt) {
            short8 a = *(const short8*)(
                smh + arow * 1024 + ((kt * 64 + (l >> 4) * 16) ^ rsw));
            acc = __builtin_amdgcn_mfma_f32_16x16x32_bf16(a, bf[16 + kt], acc, 0, 0, 0);
        }

        // ---- (6) in-register update (all 8 waves), no zl LDS ----
        if (l < 32) {
            bool msk[4];
            #pragma unroll
            for (int r = 0; r < 4; ++r)
                msk[r] = ((m_lds[(rq * 4 + r) * 16 + (t >> 5)] >> (t & 31)) & 1u) != 0u;
            float hnew[4], ov[4];
            #pragma unroll
            for (int r = 0; r < 4; ++r) {
                float z  = acc[r] + bz;
                float v1 = __shfl_xor(z, 1);
                float v2 = __shfl_xor(z, 2);
                float v3 = __shfl_xor(v1, 2);
                // gather gates: lane gt holds z[gt]; v1=z[gt^1] v2=z[gt^2] v3=z[gt^3]
                float zi = gt == 0 ? z  : gt == 1 ? v1 : gt == 2 ? v2 : v3;
                float zf = gt == 0 ? v1 : gt == 1 ? z  : gt == 2 ? v3 : v2;
                float zg = gt == 0 ? v2 : gt == 1 ? v3 : gt == 2 ? z  : v1;
                float zo = gt == 0 ? v3 : gt == 1 ? v2 : gt == 2 ? v1 : z;
                float ig = fsig(zi), fg = fsig(zf);
                float gg = ftanh_(zg), og = fsig(zo);
                float c_new = fg * c_reg[r] + ig * gg;
                float h_new = og * ftanh_(c_new);
                ov[r]   = msk[r] ? h_new : po_reg[r];
                hnew[r] = msk[r] ? h_new : h_reg[r];
                c_reg[r]  = msk[r] ? c_new : c_reg[r];
                h_reg[r]  = hnew[r];
                po_reg[r] = ov[r];
            }
            // out: lane stores row r = gt of its quad (values duplicated in group)
            out[((size_t)(obase + rq * 4 + gt) * TT + t) * HH + jg] = ov[gt];
            // h exchange: pack (jloc, jloc^1) pairs; lanes (l&7)==0 store 4 u32
            #pragma unroll
            for (int r = 0; r < 4; ++r) {
                float hp1 = __shfl_xor(hnew[r], 4);   // partner j's h
                if ((l & 7) == 0) {
                    unsigned pv = (unsigned)f2bf(hnew[r])
                                | ((unsigned)f2bf(hp1) << 16);
                    __hip_atomic_store(nxtb + (rq * 4 + r) * 256 + qb * 16 + (jloc >> 1),
                                       pv, __ATOMIC_RELAXED,
                                       __HIP_MEMORY_SCOPE_AGENT);
                }
            }
        }

        // ---- (7) stage x[t+1] (all threads, 1 short8 each) ----
        if (t + 1 < TT) {
            int row = tid >> 6, c = tid & 63;
            const float4* xp = (const float4*)(
                x + ((size_t)(obase + row) * TT + (t + 1)) * DD + 8 * c);
            float4 f0 = xp[0], f1 = xp[1];
            short8 v;
            v[0] = (short)f2bf(f0.x); v[1] = (short)f2bf(f0.y);
            v[2] = (short)f2bf(f0.z); v[3] = (short)f2bf(f0.w);
            v[4] = (short)f2bf(f1.x); v[5] = (short)f2bf(f1.y);
            v[6] = (short)f2bf(f1.z); v[7] = (short)f2bf(f1.w);
            *(short8*)(smx + row * 1024 + ((16 * c) ^ ((row & 7) << 4))) = v;
        }
        // bar C: per-wave vmcnt drain -> h sc1-stores at coherence point
        // before the flag store; smx staged for t+1; smh reads done.
        __syncthreads();

        if (tid == 0)
            __hip_atomic_store(flags + (grp * 16 + qb) * 16, (unsigned)(t + 1),
                               __ATOMIC_RELAXED, __HIP_MEMORY_SCOPE_AGENT);
    }

    if (l < 32) {
        int row_g = obase + rq * 4 + gt;
        out[OUT_HF + (size_t)row_g * HH + jg] = h_reg[gt];
        out[OUT_CF + (size_t)row_g * HH + jg] = c_reg[gt];
    }
}

extern "C" void kernel_launch(void* const* d_in, const int* in_sizes, int n_in,
                              void* d_out, int out_size, void* d_ws, size_t ws_size,
                              hipStream_t stream) {
    const float* x      = (const float*)d_in[0];
    const float* init_h = (const float*)d_in[1];
    const float* init_c = (const float*)d_in[2];
    const float* Wx     = (const float*)d_in[3];
    const float* Wr     = (const float*)d_in[4];
    const float* bias   = (const float*)d_in[5];
    const int*   mask   = (const int*)d_in[6];
    float* out = (float*)d_out;

    unsigned short* WB    = (unsigned short*)d_ws;              // 4 MB
    unsigned*       hbuf  = (unsigned*)(WB + (size_t)GG * KK);  // 128 KB
    unsigned*       flags = hbuf + 8 * 4096;                    // 8 KB
    unsigned*       mpack = flags + 2048;                       // 4 KB

    prep_kernel<<<(GG * KK + 255) / 256, 256, 0, stream>>>(
        Wx, Wr, init_h, mask, WB, hbuf, flags, mpack);

    void* args[] = { (void*)&x, (void*)&WB, (void*)&bias, (void*)&hbuf,
                     (void*)&flags, (void*)&mpack, (void*)&init_h,
                     (void*)&init_c, (void*)&out };
    (void)hipLaunchCooperativeKernel((const void*)lstm_kernel, dim3(NBLK),
                                     dim3(NTHR), args, (unsigned)LDS_BYTES,
                                     stream);
}